// Round 10
// baseline (162.649 us; speedup 1.0000x reference)
//
#include <hip/hip_runtime.h>

#define NUM_HEADS 16
#define HEAD_DIM  128
#define SEQ       2048
#define KT_STRIDE 8192   // bf16 elems per k-tile group in KF/VF (16 chunks * 512)

typedef __attribute__((ext_vector_type(8))) unsigned short us8;
typedef __attribute__((ext_vector_type(8))) __bf16 bf16x8;
typedef __attribute__((ext_vector_type(4))) float f32x4;
typedef __attribute__((ext_vector_type(16))) float f32x16;
typedef __attribute__((ext_vector_type(4))) unsigned u32x4;

static __device__ inline unsigned short f2bf(float x) {   // RNE
    union { float f; unsigned u; } v; v.f = x;
    unsigned r = v.u + 0x7FFFu + ((v.u >> 16) & 1u);
    return (unsigned short)(r >> 16);
}
static __device__ inline float bf2f(unsigned short h) {
    union { float f; unsigned u; } v; v.u = ((unsigned)h) << 16;
    return v.f;
}
static __device__ inline unsigned pk2bf(float a, float b) {
    return (unsigned)f2bf(a) | ((unsigned)f2bf(b) << 16);
}
static __device__ inline float fast_exp2(float x) {
#if __has_builtin(__builtin_amdgcn_exp2f)
    return __builtin_amdgcn_exp2f(x);
#else
    return exp2f(x);
#endif
}
static __device__ inline f32x16 mfma32(us8 a, us8 b, f32x16 c) {
    return __builtin_amdgcn_mfma_f32_32x32x16_bf16(
        __builtin_bit_cast(bf16x8, a), __builtin_bit_cast(bf16x8, b), c, 0, 0, 0);
}

// ---------- pre-pass: write K and V^T in exact 32x32x16 A-fragment order ----------
// KF[kvh][kt][kh][mat][ds][lane64][8]: elem = K[kvh][kt*64+kh*32+(lane&31)][mat*64+ds*16+(lane>>5)*8+j]
// VF[kvh][kt][kh][ks][db][lane64][8]: elem = V[kvh][kt*64+kh*32+ks*16+(lane>>5)*8+j][db*32+(lane&31)]
__global__ __launch_bounds__(256)
void prep_frag(const float* __restrict__ K, const float* __restrict__ V,
               unsigned short* __restrict__ KF, unsigned short* __restrict__ VF)
{
    const int bx  = (int)blockIdx.x, t = (int)threadIdx.x;
    const int which = bx & 1, kt = (bx >> 1) & 31, kvh = bx >> 6;
    __shared__ __align__(16) float Ls[64][132];

    const float* src = (which ? V : K) + ((size_t)kvh * SEQ + kt * 64) * HEAD_DIM;
    #pragma unroll
    for (int i = 0; i < 8; ++i) {
        const int idx = t + i * 256;
        const int r = idx >> 5, c4 = idx & 31;
        *(float4*)&Ls[r][c4 * 4] = *(const float4*)(src + (size_t)r * HEAD_DIM + c4 * 4);
    }
    __syncthreads();

    if (!which) {  // K fragments
        #pragma unroll
        for (int i = 0; i < 4; ++i) {
            const int c = t + i * 256;              // 0..1023
            const int lane = c & 63, ds = (c >> 6) & 3, mat = (c >> 8) & 1, kh = c >> 9;
            const int H = lane >> 5;
            const int row = kh * 32 + (lane & 31);
            const int dim = mat * 64 + ds * 16 + H * 8;
            u32x4 pk;
            #pragma unroll
            for (int jj = 0; jj < 4; ++jj)
                pk[jj] = pk2bf(Ls[row][dim + 2*jj], Ls[row][dim + 2*jj + 1]);
            *(us8*)(KF + ((size_t)(kvh * 32 + kt) * 16 + kh * 8 + mat * 4 + ds) * 512 + lane * 8)
                = __builtin_bit_cast(us8, pk);
        }
    } else {       // V^T fragments
        #pragma unroll
        for (int i = 0; i < 4; ++i) {
            const int c = t + i * 256;
            const int lane = c & 63, db = (c >> 6) & 3, ks = (c >> 8) & 1, kh = c >> 9;
            const int H = lane >> 5;
            const int s0 = kh * 32 + ks * 16 + H * 8;
            const int d  = db * 32 + (lane & 31);
            u32x4 pk;
            #pragma unroll
            for (int jj = 0; jj < 4; ++jj)
                pk[jj] = pk2bf(Ls[s0 + 2*jj][d], Ls[s0 + 2*jj + 1][d]);
            *(us8*)(VF + ((size_t)(kvh * 32 + kt) * 16 + kh * 8 + ks * 4 + db) * 512 + lane * 8)
                = __builtin_bit_cast(us8, pk);
        }
    }
}

// ---------- main: barrier-free streaming, register-P, one q-tile per block ----------
__global__ __launch_bounds__(256, 3)
void diff_attn_mfma8(const float* __restrict__ Q,
                     const unsigned short* __restrict__ KF,
                     const unsigned short* __restrict__ VF,
                     float* __restrict__ Out)
{
    __shared__ float cb[2][32][136];   // epilogue-only combine buffer
    __shared__ float rsb[2][2][32];

    const int t   = (int)threadIdx.x;
    const int wv  = t >> 6;
    const int ln  = t & 63;
    const int mat = wv >> 1;        // 0: softmax1 (dims 0..63), 1: softmax2 (64..127)
    const int kh  = wv & 1;         // k-half of the 64-k tile
    const int q   = ln & 31;        // q-col
    const int H   = ln >> 5;

    // grid 1024 = 16 h x 64 q-tiles; longest-first (qt = 63-idx) so the tail
    // is short blocks; scheduler backfills 3 blocks/CU (VGPR-capped)
    const int bx   = (int)blockIdx.x;
    const int h    = bx & 15;
    const int qt   = 63 - (bx >> 4);          // 63..0
    const int qpar = qt & 1;
    const int nkt  = (qt >> 1) + 1;           // 1..32
    const int q0   = qt * 32;
    const int kvh  = h >> 2;

    const unsigned short* kfb = KF + ((size_t)kvh * 32 * 16 + kh * 8 + mat * 4) * 512 + ln * 8;
    const unsigned short* vfb = VF + ((size_t)kvh * 32 * 16 + kh * 8) * 512 + ln * 8;

    const float qscale = 0.125f * 1.44269504088896340736f;  // 1/8 * log2(e)

    // ---- Q fragments (hi/lo bf16 split), once per block ----
    us8 qhi[4], qlo[4];
    {
        const float* qr = Q + ((size_t)h * SEQ + q0 + q) * HEAD_DIM + mat * 64;
        #pragma unroll
        for (int ds = 0; ds < 4; ++ds) {
            const int d0 = ds * 16 + H * 8;
            float x[8];
            *(float4*)&x[0] = *(const float4*)(qr + d0);
            *(float4*)&x[4] = *(const float4*)(qr + d0 + 4);
            us8 hi8, lo8;
            #pragma unroll
            for (int j = 0; j < 8; ++j) {
                float xs = x[j] * qscale;
                unsigned short hb = f2bf(xs);
                hi8[j] = hb;
                lo8[j] = f2bf(xs - bf2f(hb));
            }
            qhi[ds] = hi8; qlo[ds] = lo8;
        }
    }

    f32x16 o[4];                   // O^T: dim = db*32+(r&3)+8*(r>>2)+4H, q-col = q
    f32x4  rsv = (f32x4)0.f;       // row-sum partials
    #pragma unroll
    for (int i = 0; i < 4; ++i) o[i] = (f32x16)0.f;

    us8 ka[4], kan[4], va[8];
    #pragma unroll
    for (int ds = 0; ds < 4; ++ds) ka[ds] = *(const us8*)(kfb + ds * 512);

    for (int j = 0; j < nkt; ++j) {
        // V frags for THIS iter (consumed in PV after scores+exp)
        {
            const unsigned short* vb = vfb + (size_t)j * KT_STRIDE;
            #pragma unroll
            for (int c = 0; c < 8; ++c) va[c] = *(const us8*)(vb + c * 512);
        }
        // K frags prefetch for NEXT iter (full iteration of latency cover)
        if (j + 1 < nkt) {
            const unsigned short* kb = kfb + (size_t)(j + 1) * KT_STRIDE;
            #pragma unroll
            for (int ds = 0; ds < 4; ++ds) kan[ds] = *(const us8*)(kb + ds * 512);
        }

        const bool diag  = (j == nkt - 1);
        const bool skipw = diag && (qpar == 0) && (kh == 1);   // fully-masked half
        const bool triw  = diag && (kh == qpar);               // triangular half

        if (!skipw) {
            // ---- scores S^T[k][q] = K . Q^T ----
            f32x16 s = (f32x16)0.f;
            #pragma unroll
            for (int ds = 0; ds < 4; ++ds) {
                s = mfma32(ka[ds], qhi[ds], s);
                s = mfma32(ka[ds], qlo[ds], s);
            }
            // ---- exp2 + truncate to bf16 (denominator from quantized P) ----
            unsigned c[16];
            if (triw) {
                const int kg0 = j * 64 + kh * 32 + 4 * H;
                const int qg  = q0 + q;
                #pragma unroll
                for (int r = 0; r < 16; ++r) {
                    const int kg = kg0 + (r & 3) + ((r >> 2) << 3);
                    float e = (kg <= qg) ? fast_exp2(s[r]) : 0.f;
                    c[r] = __builtin_bit_cast(unsigned, e) & 0xffff0000u;
                    rsv[r & 3] += __builtin_bit_cast(float, c[r]);
                }
            } else {
                #pragma unroll
                for (int r = 0; r < 16; ++r) {
                    float e = fast_exp2(s[r]);
                    c[r] = __builtin_bit_cast(unsigned, e) & 0xffff0000u;
                    rsv[r & 3] += __builtin_bit_cast(float, c[r]);
                }
            }
            // ---- P C-frag -> B-frag in registers (lane^32 swap), then PV ----
            #pragma unroll
            for (int ks = 0; ks < 2; ++ks) {
                const unsigned pA = (c[8*ks+0] >> 16) | c[8*ks+1];
                const unsigned pB = (c[8*ks+2] >> 16) | c[8*ks+3];
                const unsigned pC = (c[8*ks+4] >> 16) | c[8*ks+5];
                const unsigned pD = (c[8*ks+6] >> 16) | c[8*ks+7];
                const unsigned x1 = H ? pA : pC;
                const unsigned x2 = H ? pB : pD;
                const unsigned t1 = (unsigned)__shfl_xor((int)x1, 32, 64);
                const unsigned t2 = (unsigned)__shfl_xor((int)x2, 32, 64);
                u32x4 bw;
                bw[0] = H ? t1 : pA;
                bw[1] = H ? t2 : pB;
                bw[2] = H ? pC : t1;
                bw[3] = H ? pD : t2;
                const us8 bp = __builtin_bit_cast(us8, bw);
                #pragma unroll
                for (int db = 0; db < 4; ++db)
                    o[db] = mfma32(va[ks * 4 + db], bp, o[db]);
            }
        }

        #pragma unroll
        for (int ds = 0; ds < 4; ++ds) ka[ds] = kan[ds];
    }

    // ---- epilogue: combine kh halves and mats through LDS ----
    __syncthreads();
    float rsc = (rsv[0] + rsv[1]) + (rsv[2] + rsv[3]);
    rsc += __shfl_xor(rsc, 32, 64);
    if (ln < 32) rsb[mat][kh][ln] = rsc;
    if (kh == 1) {
        #pragma unroll
        for (int db = 0; db < 4; ++db)
            #pragma unroll
            for (int i = 0; i < 4; ++i) {
                float4 v = { o[db][i*4+0], o[db][i*4+1], o[db][i*4+2], o[db][i*4+3] };
                *(float4*)&cb[mat][q][db * 32 + 8 * i + 4 * H] = v;
            }
    }
    __syncthreads();
    if (kh == 0) {
        const float l = rsb[mat][0][q] + rsb[mat][1][q];
        const float a = mat ? (0.16f / l) : (0.2f / l);
        #pragma unroll
        for (int db = 0; db < 4; ++db)
            #pragma unroll
            for (int i = 0; i < 4; ++i) {
                float4 v = *(float4*)&cb[mat][q][db * 32 + 8 * i + 4 * H];
                o[db][i*4+0] = (o[db][i*4+0] + v.x) * a;
                o[db][i*4+1] = (o[db][i*4+1] + v.y) * a;
                o[db][i*4+2] = (o[db][i*4+2] + v.z) * a;
                o[db][i*4+3] = (o[db][i*4+3] + v.w) * a;
            }
        if (mat == 1) {
            #pragma unroll
            for (int db = 0; db < 4; ++db)
                #pragma unroll
                for (int i = 0; i < 4; ++i) {
                    float4 v = { o[db][i*4+0], o[db][i*4+1], o[db][i*4+2], o[db][i*4+3] };
                    *(float4*)&cb[1][q][db * 32 + 8 * i + 4 * H] = v;
                }
        }
    }
    __syncthreads();
    if (wv == 0) {
        float* ob = Out + ((size_t)h * SEQ + q0 + q) * HEAD_DIM;
        #pragma unroll
        for (int db = 0; db < 4; ++db)
            #pragma unroll
            for (int i = 0; i < 4; ++i) {
                float4 v = *(float4*)&cb[1][q][db * 32 + 8 * i + 4 * H];
                float4 r;
                r.x = o[db][i*4+0] - v.x;
                r.y = o[db][i*4+1] - v.y;
                r.z = o[db][i*4+2] - v.z;
                r.w = o[db][i*4+3] - v.w;
                *(float4*)(ob + db * 32 + 8 * i + 4 * H) = r;
            }
    }
}

extern "C" void kernel_launch(void* const* d_in, const int* in_sizes, int n_in,
                              void* d_out, int out_size, void* d_ws, size_t ws_size,
                              hipStream_t stream) {
    const float* Q = (const float*)d_in[0];
    const float* K = (const float*)d_in[1];
    const float* V = (const float*)d_in[2];
    float* Out = (float*)d_out;

    unsigned short* KF = (unsigned short*)d_ws;             // 2 MB
    unsigned short* VF = KF + (size_t)4 * SEQ * HEAD_DIM;   // 2 MB

    prep_frag<<<256, 256, 0, stream>>>(K, V, KF, VF);
    diff_attn_mfma8<<<1024, 256, 0, stream>>>(Q, KF, VF, Out);
}

// Round 11
// 118.216 us; speedup vs baseline: 1.3759x; 1.3759x over previous
//
#include <hip/hip_runtime.h>

#define NUM_HEADS 16
#define HEAD_DIM  128
#define SEQ       2048
#define KT_STRIDE 8192   // bf16 elems per k-tile group in KF/VF (16 chunks * 512)

typedef __attribute__((ext_vector_type(8))) unsigned short us8;
typedef __attribute__((ext_vector_type(8))) __bf16 bf16x8;
typedef __attribute__((ext_vector_type(4))) float f32x4;
typedef __attribute__((ext_vector_type(16))) float f32x16;
typedef __attribute__((ext_vector_type(4))) unsigned u32x4;

static __device__ inline unsigned short f2bf(float x) {   // RNE
    union { float f; unsigned u; } v; v.f = x;
    unsigned r = v.u + 0x7FFFu + ((v.u >> 16) & 1u);
    return (unsigned short)(r >> 16);
}
static __device__ inline float bf2f(unsigned short h) {
    union { float f; unsigned u; } v; v.u = ((unsigned)h) << 16;
    return v.f;
}
static __device__ inline unsigned pk2bf(float a, float b) {
    return (unsigned)f2bf(a) | ((unsigned)f2bf(b) << 16);
}
static __device__ inline float fast_exp2(float x) {
#if __has_builtin(__builtin_amdgcn_exp2f)
    return __builtin_amdgcn_exp2f(x);
#else
    return exp2f(x);
#endif
}
static __device__ inline f32x16 mfma32(us8 a, us8 b, f32x16 c) {
    return __builtin_amdgcn_mfma_f32_32x32x16_bf16(
        __builtin_bit_cast(bf16x8, a), __builtin_bit_cast(bf16x8, b), c, 0, 0, 0);
}

// ---------- pre-pass: write K and V^T in exact 32x32x16 A-fragment order ----------
__global__ __launch_bounds__(256)
void prep_frag(const float* __restrict__ K, const float* __restrict__ V,
               unsigned short* __restrict__ KF, unsigned short* __restrict__ VF)
{
    const int bx  = (int)blockIdx.x, t = (int)threadIdx.x;
    const int which = bx & 1, kt = (bx >> 1) & 31, kvh = bx >> 6;
    __shared__ __align__(16) float Ls[64][132];

    const float* src = (which ? V : K) + ((size_t)kvh * SEQ + kt * 64) * HEAD_DIM;
    #pragma unroll
    for (int i = 0; i < 8; ++i) {
        const int idx = t + i * 256;
        const int r = idx >> 5, c4 = idx & 31;
        *(float4*)&Ls[r][c4 * 4] = *(const float4*)(src + (size_t)r * HEAD_DIM + c4 * 4);
    }
    __syncthreads();

    if (!which) {  // K fragments
        #pragma unroll
        for (int i = 0; i < 4; ++i) {
            const int c = t + i * 256;              // 0..1023
            const int lane = c & 63, ds = (c >> 6) & 3, mat = (c >> 8) & 1, kh = c >> 9;
            const int H = lane >> 5;
            const int row = kh * 32 + (lane & 31);
            const int dim = mat * 64 + ds * 16 + H * 8;
            u32x4 pk;
            #pragma unroll
            for (int jj = 0; jj < 4; ++jj)
                pk[jj] = pk2bf(Ls[row][dim + 2*jj], Ls[row][dim + 2*jj + 1]);
            *(us8*)(KF + ((size_t)(kvh * 32 + kt) * 16 + kh * 8 + mat * 4 + ds) * 512 + lane * 8)
                = __builtin_bit_cast(us8, pk);
        }
    } else {       // V^T fragments
        #pragma unroll
        for (int i = 0; i < 4; ++i) {
            const int c = t + i * 256;
            const int lane = c & 63, db = (c >> 6) & 3, ks = (c >> 8) & 1, kh = c >> 9;
            const int H = lane >> 5;
            const int s0 = kh * 32 + ks * 16 + H * 8;
            const int d  = db * 32 + (lane & 31);
            u32x4 pk;
            #pragma unroll
            for (int jj = 0; jj < 4; ++jj)
                pk[jj] = pk2bf(Ls[s0 + 2*jj][d], Ls[s0 + 2*jj + 1][d]);
            *(us8*)(VF + ((size_t)(kvh * 32 + kt) * 16 + kh * 8 + ks * 4 + db) * 512 + lane * 8)
                = __builtin_bit_cast(us8, pk);
        }
    }
}

// ---------- main: streaming, register-P, score-pipelined, equal-length blocks ----------
__global__ __launch_bounds__(256, 2)
void diff_attn_mfma9(const float* __restrict__ Q,
                     const unsigned short* __restrict__ KF,
                     const unsigned short* __restrict__ VF,
                     float* __restrict__ Out)
{
    __shared__ float cb[2][32][136];   // epilogue-only combine buffer
    __shared__ float rsb[2][2][32];

    const int t   = (int)threadIdx.x;
    const int wv  = t >> 6;
    const int ln  = t & 63;
    const int mat = wv >> 1;        // 0: softmax1 (dims 0..63), 1: softmax2 (64..127)
    const int kh  = wv & 1;         // k-half of the 64-k tile
    const int q   = ln & 31;        // q-col
    const int H   = ln >> 5;

    // grid 512 = 16 h x 32 pair-slots; block does q-tiles (idx, 63-idx) sequentially
    // -> every block runs exactly 33 main iterations (equal duration, 2 blocks/CU)
    const int bx   = (int)blockIdx.x;
    const int h    = bx & 15;
    const int idx  = bx >> 4;                 // 0..31
    const int qtA  = idx, qtB = 63 - idx;
    const int nktA = (qtA >> 1) + 1;          // nktA + nktB = 33
    const int kvh  = h >> 2;

    const unsigned short* kfb = KF + ((size_t)kvh * 32 * 16 + kh * 8 + mat * 4) * 512 + ln * 8;
    const unsigned short* vfb = VF + ((size_t)kvh * 32 * 16 + kh * 8) * 512 + ln * 8;

    const float qscale = 0.125f * 1.44269504088896340736f;  // 1/8 * log2(e)

    us8 qhi[4], qlo[4];
    auto loadQ = [&](int q0c) {
        const float* qr = Q + ((size_t)h * SEQ + q0c + q) * HEAD_DIM + mat * 64;
        #pragma unroll
        for (int ds = 0; ds < 4; ++ds) {
            const int d0 = ds * 16 + H * 8;
            float x[8];
            *(float4*)&x[0] = *(const float4*)(qr + d0);
            *(float4*)&x[4] = *(const float4*)(qr + d0 + 4);
            us8 hi8, lo8;
            #pragma unroll
            for (int j = 0; j < 8; ++j) {
                float xs = x[j] * qscale;
                unsigned short hb = f2bf(xs);
                hi8[j] = hb;
                lo8[j] = f2bf(xs - bf2f(hb));
            }
            qhi[ds] = hi8; qlo[ds] = lo8;
        }
    };

    f32x16 o[4];                   // O^T: dim = db*32+(r&3)+8*(r>>2)+4H, q-col = q
    f32x4  rsv;                    // row-sum partials

    // epilogue: combine kh halves and mats through LDS
    auto epilogue = [&](int q0c) {
        __syncthreads();
        float rsc = (rsv[0] + rsv[1]) + (rsv[2] + rsv[3]);
        rsc += __shfl_xor(rsc, 32, 64);
        if (ln < 32) rsb[mat][kh][ln] = rsc;
        if (kh == 1) {
            #pragma unroll
            for (int db = 0; db < 4; ++db)
                #pragma unroll
                for (int i = 0; i < 4; ++i) {
                    float4 v = { o[db][i*4+0], o[db][i*4+1], o[db][i*4+2], o[db][i*4+3] };
                    *(float4*)&cb[mat][q][db * 32 + 8 * i + 4 * H] = v;
                }
        }
        __syncthreads();
        if (kh == 0) {
            const float l = rsb[mat][0][q] + rsb[mat][1][q];
            const float a = mat ? (0.16f / l) : (0.2f / l);
            #pragma unroll
            for (int db = 0; db < 4; ++db)
                #pragma unroll
                for (int i = 0; i < 4; ++i) {
                    float4 v = *(float4*)&cb[mat][q][db * 32 + 8 * i + 4 * H];
                    o[db][i*4+0] = (o[db][i*4+0] + v.x) * a;
                    o[db][i*4+1] = (o[db][i*4+1] + v.y) * a;
                    o[db][i*4+2] = (o[db][i*4+2] + v.z) * a;
                    o[db][i*4+3] = (o[db][i*4+3] + v.w) * a;
                }
            if (mat == 1) {
                #pragma unroll
                for (int db = 0; db < 4; ++db)
                    #pragma unroll
                    for (int i = 0; i < 4; ++i) {
                        float4 v = { o[db][i*4+0], o[db][i*4+1], o[db][i*4+2], o[db][i*4+3] };
                        *(float4*)&cb[1][q][db * 32 + 8 * i + 4 * H] = v;
                    }
            }
        }
        __syncthreads();
        if (wv == 0) {
            float* ob = Out + ((size_t)h * SEQ + q0c + q) * HEAD_DIM;
            #pragma unroll
            for (int db = 0; db < 4; ++db)
                #pragma unroll
                for (int i = 0; i < 4; ++i) {
                    float4 v = *(float4*)&cb[1][q][db * 32 + 8 * i + 4 * H];
                    float4 r;
                    r.x = o[db][i*4+0] - v.x;
                    r.y = o[db][i*4+1] - v.y;
                    r.z = o[db][i*4+2] - v.z;
                    r.w = o[db][i*4+3] - v.w;
                    *(float4*)(ob + db * 32 + 8 * i + 4 * H) = r;
                }
        }
    };

    // one causal segment: k-tiles 0..nseg-1 against the current Q-frags.
    // Scores pipelined one k-tile ahead: exp2(S_j) overlaps MFMA of S_{j+1}.
    auto run_seg = [&](int q0c, int nseg) {
        us8 ka[4], kan[4], va[8];
        #pragma unroll
        for (int ds = 0; ds < 4; ++ds) ka[ds] = *(const us8*)(kfb + ds * 512);
        f32x16 s = (f32x16)0.f;
        #pragma unroll
        for (int ds = 0; ds < 4; ++ds) {       // prologue: scores for k-tile 0
            s = mfma32(ka[ds], qhi[ds], s);
            s = mfma32(ka[ds], qlo[ds], s);
        }
        if (nseg > 1) {
            #pragma unroll
            for (int ds = 0; ds < 4; ++ds) ka[ds] = *(const us8*)(kfb + KT_STRIDE + ds * 512);
        }

        for (int j = 0; j < nseg; ++j) {
            // V frags for THIS iter (consumed in PV at iter end)
            {
                const unsigned short* vb = vfb + (size_t)j * KT_STRIDE;
                #pragma unroll
                for (int c = 0; c < 8; ++c) va[c] = *(const us8*)(vb + c * 512);
            }
            // K frags for iter j+2 (ka currently holds j+1)
            if (j + 2 < nseg) {
                const unsigned short* kb = kfb + (size_t)(j + 2) * KT_STRIDE;
                #pragma unroll
                for (int ds = 0; ds < 4; ++ds) kan[ds] = *(const us8*)(kb + ds * 512);
            }

            // ---- scores for NEXT k-tile (independent MFMA work) ----
            f32x16 sn = (f32x16)0.f;
            if (j + 1 < nseg) {
                #pragma unroll
                for (int ds = 0; ds < 4; ++ds) {
                    sn = mfma32(ka[ds], qhi[ds], sn);
                    sn = mfma32(ka[ds], qlo[ds], sn);
                }
            }

            // ---- exp2 + truncate to bf16 (denominator from quantized P) ----
            unsigned c[16];
            if (j == nseg - 1) {               // diagonal tile: uniform mask
                const int kg0 = j * 64 + kh * 32 + 4 * H;
                const int qg  = q0c + q;
                #pragma unroll
                for (int r = 0; r < 16; ++r) {
                    const int kg = kg0 + (r & 3) + ((r >> 2) << 3);
                    float e = (kg <= qg) ? fast_exp2(s[r]) : 0.f;
                    c[r] = __builtin_bit_cast(unsigned, e) & 0xffff0000u;
                    rsv[r & 3] += __builtin_bit_cast(float, c[r]);
                }
            } else {
                #pragma unroll
                for (int r = 0; r < 16; ++r) {
                    float e = fast_exp2(s[r]);
                    c[r] = __builtin_bit_cast(unsigned, e) & 0xffff0000u;
                    rsv[r & 3] += __builtin_bit_cast(float, c[r]);
                }
            }

            // ---- P C-frag -> B-frag in registers (lane^32 swap), then PV ----
            #pragma unroll
            for (int ks = 0; ks < 2; ++ks) {
                const unsigned pA = (c[8*ks+0] >> 16) | c[8*ks+1];
                const unsigned pB = (c[8*ks+2] >> 16) | c[8*ks+3];
                const unsigned pC = (c[8*ks+4] >> 16) | c[8*ks+5];
                const unsigned pD = (c[8*ks+6] >> 16) | c[8*ks+7];
                const unsigned x1 = H ? pA : pC;
                const unsigned x2 = H ? pB : pD;
                const unsigned t1 = (unsigned)__shfl_xor((int)x1, 32, 64);
                const unsigned t2 = (unsigned)__shfl_xor((int)x2, 32, 64);
                u32x4 bw;
                bw[0] = H ? t1 : pA;
                bw[1] = H ? t2 : pB;
                bw[2] = H ? pC : t1;
                bw[3] = H ? pD : t2;
                const us8 bp = __builtin_bit_cast(us8, bw);
                #pragma unroll
                for (int db = 0; db < 4; ++db)
                    o[db] = mfma32(va[ks * 4 + db], bp, o[db]);
            }

            #pragma unroll
            for (int ds = 0; ds < 4; ++ds) ka[ds] = kan[ds];
            s = sn;
        }
    };

    // ---- q-tile A then q-tile B (33 main iterations total, every block) ----
    loadQ(qtA * 32);
    #pragma unroll
    for (int i = 0; i < 4; ++i) o[i] = (f32x16)0.f;
    rsv = (f32x4)0.f;
    run_seg(qtA * 32, nktA);
    epilogue(qtA * 32);

    loadQ(qtB * 32);
    #pragma unroll
    for (int i = 0; i < 4; ++i) o[i] = (f32x16)0.f;
    rsv = (f32x4)0.f;
    run_seg(qtB * 32, 33 - nktA);
    epilogue(qtB * 32);
}

extern "C" void kernel_launch(void* const* d_in, const int* in_sizes, int n_in,
                              void* d_out, int out_size, void* d_ws, size_t ws_size,
                              hipStream_t stream) {
    const float* Q = (const float*)d_in[0];
    const float* K = (const float*)d_in[1];
    const float* V = (const float*)d_in[2];
    float* Out = (float*)d_out;

    unsigned short* KF = (unsigned short*)d_ws;             // 2 MB
    unsigned short* VF = KF + (size_t)4 * SEQ * HEAD_DIM;   // 2 MB

    prep_frag<<<256, 256, 0, stream>>>(K, V, KF, VF);
    diff_attn_mfma9<<<512, 256, 0, stream>>>(Q, KF, VF, Out);
}

// Round 12
// 111.891 us; speedup vs baseline: 1.4536x; 1.0565x over previous
//
#include <hip/hip_runtime.h>

#define NUM_HEADS 16
#define HEAD_DIM  128
#define SEQ       2048
#define KT_STRIDE 8192   // bf16 elems per k-tile group in KF/VF (16 chunks * 512)

typedef __attribute__((ext_vector_type(8))) unsigned short us8;
typedef __attribute__((ext_vector_type(8))) __bf16 bf16x8;
typedef __attribute__((ext_vector_type(4))) float f32x4;
typedef __attribute__((ext_vector_type(16))) float f32x16;
typedef __attribute__((ext_vector_type(4))) unsigned u32x4;

static __device__ inline unsigned short f2bf(float x) {   // RNE
    union { float f; unsigned u; } v; v.f = x;
    unsigned r = v.u + 0x7FFFu + ((v.u >> 16) & 1u);
    return (unsigned short)(r >> 16);
}
static __device__ inline unsigned pk2bf(float a, float b) {
    return (unsigned)f2bf(a) | ((unsigned)f2bf(b) << 16);
}
static __device__ inline float fast_exp2(float x) {
#if __has_builtin(__builtin_amdgcn_exp2f)
    return __builtin_amdgcn_exp2f(x);
#else
    return exp2f(x);
#endif
}
// pack hi16(clo) into lo half, hi16(chi) into hi half (both truncated bf16)
static __device__ inline unsigned pack_hi(unsigned clo, unsigned chi) {
#if __has_builtin(__builtin_amdgcn_perm)
    return __builtin_amdgcn_perm(chi, clo, 0x07060302u);
#else
    return (clo >> 16) | (chi & 0xffff0000u);
#endif
}
static __device__ inline f32x16 mfma32(us8 a, us8 b, f32x16 c) {
    return __builtin_amdgcn_mfma_f32_32x32x16_bf16(
        __builtin_bit_cast(bf16x8, a), __builtin_bit_cast(bf16x8, b), c, 0, 0, 0);
}

// ---------- pre-pass: write K and V^T in exact 32x32x16 A-fragment order ----------
__global__ __launch_bounds__(256)
void prep_frag(const float* __restrict__ K, const float* __restrict__ V,
               unsigned short* __restrict__ KF, unsigned short* __restrict__ VF)
{
    const int bx  = (int)blockIdx.x, t = (int)threadIdx.x;
    const int which = bx & 1, kt = (bx >> 1) & 31, kvh = bx >> 6;
    __shared__ __align__(16) float Ls[64][132];

    const float* src = (which ? V : K) + ((size_t)kvh * SEQ + kt * 64) * HEAD_DIM;
    #pragma unroll
    for (int i = 0; i < 8; ++i) {
        const int idx = t + i * 256;
        const int r = idx >> 5, c4 = idx & 31;
        *(float4*)&Ls[r][c4 * 4] = *(const float4*)(src + (size_t)r * HEAD_DIM + c4 * 4);
    }
    __syncthreads();

    if (!which) {  // K fragments
        #pragma unroll
        for (int i = 0; i < 4; ++i) {
            const int c = t + i * 256;              // 0..1023
            const int lane = c & 63, ds = (c >> 6) & 3, mat = (c >> 8) & 1, kh = c >> 9;
            const int H = lane >> 5;
            const int row = kh * 32 + (lane & 31);
            const int dim = mat * 64 + ds * 16 + H * 8;
            u32x4 pk;
            #pragma unroll
            for (int jj = 0; jj < 4; ++jj)
                pk[jj] = pk2bf(Ls[row][dim + 2*jj], Ls[row][dim + 2*jj + 1]);
            *(us8*)(KF + ((size_t)(kvh * 32 + kt) * 16 + kh * 8 + mat * 4 + ds) * 512 + lane * 8)
                = __builtin_bit_cast(us8, pk);
        }
    } else {       // V^T fragments
        #pragma unroll
        for (int i = 0; i < 4; ++i) {
            const int c = t + i * 256;
            const int lane = c & 63, db = (c >> 6) & 3, ks = (c >> 8) & 1, kh = c >> 9;
            const int H = lane >> 5;
            const int s0 = kh * 32 + ks * 16 + H * 8;
            const int d  = db * 32 + (lane & 31);
            u32x4 pk;
            #pragma unroll
            for (int jj = 0; jj < 4; ++jj)
                pk[jj] = pk2bf(Ls[s0 + 2*jj][d], Ls[s0 + 2*jj + 1][d]);
            *(us8*)(VF + ((size_t)(kvh * 32 + kt) * 16 + kh * 8 + ks * 4 + db) * 512 + lane * 8)
                = __builtin_bit_cast(us8, pk);
        }
    }
}

// ---------- main: streaming, register-P, pipelined + 2x unrolled, equal-length blocks ----------
__global__ __launch_bounds__(256, 2)
void diff_attn_mfma10(const float* __restrict__ Q,
                      const unsigned short* __restrict__ KF,
                      const unsigned short* __restrict__ VF,
                      float* __restrict__ Out)
{
    __shared__ float cb[2][32][136];   // epilogue-only combine buffer
    __shared__ float rsb[2][2][32];

    const int t   = (int)threadIdx.x;
    const int wv  = t >> 6;
    const int ln  = t & 63;
    const int mat = wv >> 1;        // 0: softmax1 (dims 0..63), 1: softmax2 (64..127)
    const int kh  = wv & 1;         // k-half of the 64-k tile
    const int q   = ln & 31;        // q-col
    const int H   = ln >> 5;

    // grid 512 = 16 h x 32 pair-slots; block does q-tiles (idx, 63-idx) sequentially
    const int bx   = (int)blockIdx.x;
    const int h    = bx & 15;
    const int idx  = bx >> 4;                 // 0..31
    const int qtA  = idx, qtB = 63 - idx;
    const int nktA = (qtA >> 1) + 1;          // nktA + nktB = 33
    const int kvh  = h >> 2;

    const unsigned short* kfb = KF + ((size_t)kvh * 32 * 16 + kh * 8 + mat * 4) * 512 + ln * 8;
    const unsigned short* vfb = VF + ((size_t)kvh * 32 * 16 + kh * 8) * 512 + ln * 8;

    const float qscale = 0.125f * 1.44269504088896340736f;  // 1/8 * log2(e)

    us8 qhi[4];
    auto loadQ = [&](int q0c) {
        const float* qr = Q + ((size_t)h * SEQ + q0c + q) * HEAD_DIM + mat * 64;
        #pragma unroll
        for (int ds = 0; ds < 4; ++ds) {
            const int d0 = ds * 16 + H * 8;
            float x[8];
            *(float4*)&x[0] = *(const float4*)(qr + d0);
            *(float4*)&x[4] = *(const float4*)(qr + d0 + 4);
            us8 hi8;
            #pragma unroll
            for (int j = 0; j < 8; ++j) hi8[j] = f2bf(x[j] * qscale);
            qhi[ds] = hi8;
        }
    };

    f32x16 o[4];                   // O^T: dim = db*32+(r&3)+8*(r>>2)+4H, q-col = q
    f32x4  rsv;                    // row-sum partials

    auto epilogue = [&](int q0c) {
        __syncthreads();
        float rsc = (rsv[0] + rsv[1]) + (rsv[2] + rsv[3]);
        rsc += __shfl_xor(rsc, 32, 64);
        if (ln < 32) rsb[mat][kh][ln] = rsc;
        if (kh == 1) {
            #pragma unroll
            for (int db = 0; db < 4; ++db)
                #pragma unroll
                for (int i = 0; i < 4; ++i) {
                    float4 v = { o[db][i*4+0], o[db][i*4+1], o[db][i*4+2], o[db][i*4+3] };
                    *(float4*)&cb[mat][q][db * 32 + 8 * i + 4 * H] = v;
                }
        }
        __syncthreads();
        if (kh == 0) {
            const float l = rsb[mat][0][q] + rsb[mat][1][q];
            const float a = mat ? (0.16f / l) : (0.2f / l);
            #pragma unroll
            for (int db = 0; db < 4; ++db)
                #pragma unroll
                for (int i = 0; i < 4; ++i) {
                    float4 v = *(float4*)&cb[mat][q][db * 32 + 8 * i + 4 * H];
                    o[db][i*4+0] = (o[db][i*4+0] + v.x) * a;
                    o[db][i*4+1] = (o[db][i*4+1] + v.y) * a;
                    o[db][i*4+2] = (o[db][i*4+2] + v.z) * a;
                    o[db][i*4+3] = (o[db][i*4+3] + v.w) * a;
                }
            if (mat == 1) {
                #pragma unroll
                for (int db = 0; db < 4; ++db)
                    #pragma unroll
                    for (int i = 0; i < 4; ++i) {
                        float4 v = { o[db][i*4+0], o[db][i*4+1], o[db][i*4+2], o[db][i*4+3] };
                        *(float4*)&cb[1][q][db * 32 + 8 * i + 4 * H] = v;
                    }
            }
        }
        __syncthreads();
        if (wv == 0) {
            float* ob = Out + ((size_t)h * SEQ + q0c + q) * HEAD_DIM;
            #pragma unroll
            for (int db = 0; db < 4; ++db)
                #pragma unroll
                for (int i = 0; i < 4; ++i) {
                    float4 v = *(float4*)&cb[1][q][db * 32 + 8 * i + 4 * H];
                    float4 r;
                    r.x = o[db][i*4+0] - v.x;
                    r.y = o[db][i*4+1] - v.y;
                    r.z = o[db][i*4+2] - v.z;
                    r.w = o[db][i*4+3] - v.w;
                    *(float4*)(ob + db * 32 + 8 * i + 4 * H) = r;
                }
        }
    };

    // one causal segment, scores pipelined one tile ahead, 2x unrolled (no reg ping-pong movs)
    auto run_seg = [&](int q0c, int nseg) {
        us8 kaA[4], kaB[4];

        // body(j): kaIn holds K(j+1); kaOut <- K(j+2); sIn = S(j); sOut <- S(j+1)
        auto body = [&](int j, us8 (&kaIn)[4], us8 (&kaOut)[4], f32x16& sIn, f32x16& sOut) {
            us8 va[8];
            {
                const unsigned short* vb = vfb + (size_t)j * KT_STRIDE;
                #pragma unroll
                for (int c = 0; c < 8; ++c) va[c] = *(const us8*)(vb + c * 512);
            }
            if (j + 2 < nseg) {
                const unsigned short* kb = kfb + (size_t)(j + 2) * KT_STRIDE;
                #pragma unroll
                for (int ds = 0; ds < 4; ++ds) kaOut[ds] = *(const us8*)(kb + ds * 512);
            }
            // scores for next k-tile (independent MFMA work covering this iter's VALU)
            sOut = (f32x16)0.f;
            if (j + 1 < nseg) {
                #pragma unroll
                for (int ds = 0; ds < 4; ++ds) sOut = mfma32(kaIn[ds], qhi[ds], sOut);
            }
            // exp2 (+ causal mask on diagonal tile only)
            unsigned c[16];
            if (j == nseg - 1) {
                const int kg0 = j * 64 + kh * 32 + 4 * H;
                const int qg  = q0c + q;
                #pragma unroll
                for (int r = 0; r < 16; ++r) {
                    const int kg = kg0 + (r & 3) + ((r >> 2) << 3);
                    float e = (kg <= qg) ? fast_exp2(sIn[r]) : 0.f;
                    c[r] = __builtin_bit_cast(unsigned, e);
                }
            } else {
                #pragma unroll
                for (int r = 0; r < 16; ++r)
                    c[r] = __builtin_bit_cast(unsigned, fast_exp2(sIn[r]));
            }
            // pack to bf16 pairs (truncation), accumulate denominator from QUANTIZED P,
            // C-frag -> B-frag via lane^32 swap, then PV
            #pragma unroll
            for (int ks = 0; ks < 2; ++ks) {
                const unsigned pA = pack_hi(c[8*ks+0], c[8*ks+1]);
                const unsigned pB = pack_hi(c[8*ks+2], c[8*ks+3]);
                const unsigned pC = pack_hi(c[8*ks+4], c[8*ks+5]);
                const unsigned pD = pack_hi(c[8*ks+6], c[8*ks+7]);
                rsv[0] += __builtin_bit_cast(float, pA << 16);
                rsv[1] += __builtin_bit_cast(float, pA & 0xffff0000u);
                rsv[2] += __builtin_bit_cast(float, pB << 16);
                rsv[3] += __builtin_bit_cast(float, pB & 0xffff0000u);
                rsv[0] += __builtin_bit_cast(float, pC << 16);
                rsv[1] += __builtin_bit_cast(float, pC & 0xffff0000u);
                rsv[2] += __builtin_bit_cast(float, pD << 16);
                rsv[3] += __builtin_bit_cast(float, pD & 0xffff0000u);
                const unsigned x1 = H ? pA : pC;
                const unsigned x2 = H ? pB : pD;
                const unsigned t1 = (unsigned)__shfl_xor((int)x1, 32, 64);
                const unsigned t2 = (unsigned)__shfl_xor((int)x2, 32, 64);
                u32x4 bw;
                bw[0] = H ? t1 : pA;
                bw[1] = H ? t2 : pB;
                bw[2] = H ? pC : t1;
                bw[3] = H ? pD : t2;
                const us8 bp = __builtin_bit_cast(us8, bw);
                #pragma unroll
                for (int db = 0; db < 4; ++db)
                    o[db] = mfma32(va[ks * 4 + db], bp, o[db]);
            }
        };

        f32x16 s0, s1;
        #pragma unroll
        for (int ds = 0; ds < 4; ++ds) kaA[ds] = *(const us8*)(kfb + ds * 512);
        s0 = (f32x16)0.f;
        #pragma unroll
        for (int ds = 0; ds < 4; ++ds) s0 = mfma32(kaA[ds], qhi[ds], s0);
        if (nseg > 1) {
            #pragma unroll
            for (int ds = 0; ds < 4; ++ds) kaA[ds] = *(const us8*)(kfb + KT_STRIDE + ds * 512);
        }

        int j = 0;
        for (; j + 2 <= nseg; j += 2) {
            body(j,     kaA, kaB, s0, s1);
            body(j + 1, kaB, kaA, s1, s0);
        }
        if (j < nseg) body(j, kaA, kaB, s0, s1);
    };

    // ---- q-tile A then q-tile B (33 main iterations total, every block) ----
    loadQ(qtA * 32);
    #pragma unroll
    for (int i = 0; i < 4; ++i) o[i] = (f32x16)0.f;
    rsv = (f32x4)0.f;
    run_seg(qtA * 32, nktA);
    epilogue(qtA * 32);

    loadQ(qtB * 32);
    #pragma unroll
    for (int i = 0; i < 4; ++i) o[i] = (f32x16)0.f;
    rsv = (f32x4)0.f;
    run_seg(qtB * 32, 33 - nktA);
    epilogue(qtB * 32);
}

extern "C" void kernel_launch(void* const* d_in, const int* in_sizes, int n_in,
                              void* d_out, int out_size, void* d_ws, size_t ws_size,
                              hipStream_t stream) {
    const float* Q = (const float*)d_in[0];
    const float* K = (const float*)d_in[1];
    const float* V = (const float*)d_in[2];
    float* Out = (float*)d_out;

    unsigned short* KF = (unsigned short*)d_ws;             // 2 MB
    unsigned short* VF = KF + (size_t)4 * SEQ * HEAD_DIM;   // 2 MB

    prep_frag<<<256, 256, 0, stream>>>(K, V, KF, VF);
    diff_attn_mfma10<<<512, 256, 0, stream>>>(Q, KF, VF, Out);
}